// Round 21
// baseline (337.093 us; speedup 1.0000x reference)
//
#include <hip/hip_runtime.h>
#include <math.h>

#define B_ 32
#define N_ 128
#define E_ 16384
#define EPS_ 1e-5f

typedef short short8v __attribute__((ext_vector_type(8)));
typedef float f32x4v __attribute__((ext_vector_type(4)));

#define FADD(p, v) unsafeAtomicAdd((p), (v))

// ---- ws layout (float offsets): round-0 proven footprint ----
#define WS_MAGG    4608     // B*N*72  (Pmid, then stats partials, then magg)
#define WS_AGG     299520   // B*N*4
#define WS_CNT     315904   // B*N (float counts, written by k_scan)
#define WS_ZERO_END 320000
#define WS_AE      320000
#define WS_BE      320072
#define WS_AH      320144
#define WS_BH      320216
#define WS_HIST    320288   // int[4096] -- outside Ptop (r19 fix)
#define WS_ZH1     325472   // B*N*72: P_top, then {perm+tables}, then zh1
#define WS_PERM    325472   // ushort[B*E] (written after Ptop dies)
#define WS_OFFS    591712   // int[4096]  (written after Ptop dies)
#define WS_CURS    595808   // int[4096]  (end 599904 < 620384)

#define HOUT_OFF 0
#define XOUT_OFF 294912
#define M_OFF    311296

#define NSTAT_T 147456
#define MSTR 88            // mS row stride in shorts: 176B = 44 banks -> 2-way max

static __device__ __forceinline__ short f2bf(float f) {
    unsigned int u = __builtin_bit_cast(unsigned int, f);
    u += 0x7FFFu + ((u >> 16) & 1u);
    return (short)(u >> 16);
}
static __device__ __forceinline__ unsigned int pack2(float a, float b) {
    return (unsigned int)(unsigned short)f2bf(a) | ((unsigned int)(unsigned short)f2bf(b) << 16);
}
static __device__ __forceinline__ float b2f_lo(unsigned int u) {
    return __builtin_bit_cast(float, u << 16);
}
static __device__ __forceinline__ float b2f_hi(unsigned int u) {
    return __builtin_bit_cast(float, u & 0xFFFF0000u);
}

// ---- node projections (q/which block-uniform) ----
__global__ __launch_bounds__(256) void k_nodeproj(
    const float* __restrict__ h, const float* __restrict__ We1,
    float* __restrict__ Ptop, float* __restrict__ Pmid)
{
    int blk = blockIdx.x;                 // 128
    int rowBlk = blk >> 3, sub = blk & 7;
    int which = sub >> 2, q = sub & 3;
    int row = rowBlk * 256 + threadIdx.x; // < 4096
    int c0 = q * 18;
    const float4* h4 = (const float4*)(h + (size_t)row * 72);
    const float* base = We1 + which * 5184 + c0;
    float acc[18];
#pragma unroll
    for (int c = 0; c < 18; ++c) acc[c] = 0.f;
    for (int kc = 0; kc < 18; ++kc) {
        float4 a = h4[kc];
        const float* wr = base + (kc * 4) * 72;
#pragma unroll
        for (int c = 0; c < 18; ++c)
            acc[c] = fmaf(a.x, wr[c], fmaf(a.y, wr[72 + c], fmaf(a.z, wr[144 + c], fmaf(a.w, wr[216 + c], acc[c]))));
    }
    float* P = (which ? Pmid : Ptop) + (size_t)row * 72 + c0;
#pragma unroll
    for (int c = 0; c < 18; ++c) P[c] = acc[c];
}

// ---- edge pass 1: z1(bf16, 144B in each 288B m-slot) + per-block edge histogram ----
__global__ __launch_bounds__(256) void k_edge1v4(
    const float* __restrict__ x,
    const int* __restrict__ ei, const int* __restrict__ ej,
    const float* __restrict__ Ptop, const float* __restrict__ Pmid,
    const float* __restrict__ We1,
    unsigned short* __restrict__ zG, int* __restrict__ hist)
{
    __shared__ int lh[128];
    int t = threadIdx.x;
    if (t < 128) lh[t] = 0;
    __syncthreads();

    int eg = blockIdx.x * 256 + t;
    int b = eg >> 14;
    int i = ei[eg], j = ej[eg];
    atomicAdd(&lh[i], 1);
    int ri = b * N_ + i, rj = b * N_ + j;

    float4 xi = *(const float4*)(x + ri * 4);
    float4 xj = *(const float4*)(x + rj * 4);
    float xdx = xi.x - xj.x, xdy = xi.y - xj.y, xdz = xi.z - xj.z, xdw = xi.w - xj.w;
    float nsq = xdx * xdx - xdy * xdy - xdz * xdz - xdw * xdw;
    float dsq = xi.x * xj.x - xi.y * xj.y - xi.z * xj.z - xi.w * xj.w;
    float norms = copysignf(log1pf(fabsf(nsq)), nsq);
    float dots  = copysignf(log1pf(fabsf(dsq)), dsq);

    const float4* pt4 = (const float4*)(Ptop + (size_t)ri * 72);
    const float4* pm4 = (const float4*)(Pmid + (size_t)rj * 72);
    const float* w144 = We1 + 144 * 72;
    const float* w145 = We1 + 145 * 72;
    uint4* zr = (uint4*)(zG + (size_t)eg * 144);

#pragma unroll
    for (int g = 0; g < 9; ++g) {
        float4 a0 = pt4[2 * g],     bq0 = pm4[2 * g];
        float4 a1 = pt4[2 * g + 1], bq1 = pm4[2 * g + 1];
        float4 wa0 = *(const float4*)(w144 + 8 * g);
        float4 wb0 = *(const float4*)(w145 + 8 * g);
        float4 wa1 = *(const float4*)(w144 + 8 * g + 4);
        float4 wb1 = *(const float4*)(w145 + 8 * g + 4);
        float r0 = fmaf(norms, wa0.x, fmaf(dots, wb0.x, a0.x + bq0.x));
        float r1 = fmaf(norms, wa0.y, fmaf(dots, wb0.y, a0.y + bq0.y));
        float r2 = fmaf(norms, wa0.z, fmaf(dots, wb0.z, a0.z + bq0.z));
        float r3 = fmaf(norms, wa0.w, fmaf(dots, wb0.w, a0.w + bq0.w));
        float r4 = fmaf(norms, wa1.x, fmaf(dots, wb1.x, a1.x + bq1.x));
        float r5 = fmaf(norms, wa1.y, fmaf(dots, wb1.y, a1.y + bq1.y));
        float r6 = fmaf(norms, wa1.z, fmaf(dots, wb1.z, a1.z + bq1.z));
        float r7 = fmaf(norms, wa1.w, fmaf(dots, wb1.w, a1.w + bq1.w));
        uint4 u;
        u.x = pack2(r0, r1); u.y = pack2(r2, r3);
        u.z = pack2(r4, r5); u.w = pack2(r6, r7);
        zr[g] = u;
    }
    __syncthreads();
    if (t < 128) {
        int v = lh[t];
        if (v) atomicAdd(&hist[b * N_ + t], v);
    }
}

// -------------------- sort: scan / scatter --------------------
__global__ void k_scan(const int* __restrict__ hist, int* __restrict__ offs,
                       int* __restrict__ curs, float* __restrict__ cnt)
{
    __shared__ int sh[128];
    int b = blockIdx.x, n = threadIdx.x;  // 32 x 128
    int cv = hist[b * N_ + n];
    sh[n] = cv;
    __syncthreads();
    for (int off = 1; off < 128; off <<= 1) {
        int v = (n >= off) ? sh[n - off] : 0;
        __syncthreads();
        sh[n] += v;
        __syncthreads();
    }
    int excl = sh[n] - cv;
    offs[b * N_ + n] = excl;
    curs[b * N_ + n] = excl;
    cnt[b * N_ + n] = (float)cv;
}

__global__ __launch_bounds__(256) void k_scatter(
    const int* __restrict__ ei, int* __restrict__ curs,
    unsigned short* __restrict__ perm)
{
    int eg = blockIdx.x * 256 + threadIdx.x;  // < 524288
    int b = eg >> 14;
    int i = ei[eg];
    int pos = atomicAdd(&curs[b * N_ + i], 1);
    perm[(size_t)b * E_ + pos] = (unsigned short)(eg & (E_ - 1));
}

// ---- BN stats over bf16 z: uint4 loads, 8 channels/thread (G13) ----
__global__ __launch_bounds__(256) void k_stats_bf(
    const unsigned short* __restrict__ zG,
    float* __restrict__ sPart, float* __restrict__ qPart)
{
    int tid = blockIdx.x * 256 + threadIdx.x;   // < 18432 (72 blocks)
    int c8 = tid % 9, e0 = tid / 9;             // e0: 0..2047, 8 chans per thread
    float s[8], q[8];
#pragma unroll
    for (int j = 0; j < 8; ++j) { s[j] = 0.f; q[j] = 0.f; }
    size_t idx = (size_t)e0 * 144 + c8 * 8;
    const size_t step = (size_t)2048 * 144;
    for (int k = 0; k < 256; ++k, idx += step) {
        uint4 u = *(const uint4*)(zG + idx);
        float v0 = b2f_lo(u.x), v1 = b2f_hi(u.x);
        float v2 = b2f_lo(u.y), v3 = b2f_hi(u.y);
        float v4 = b2f_lo(u.z), v5 = b2f_hi(u.z);
        float v6 = b2f_lo(u.w), v7 = b2f_hi(u.w);
        s[0] += v0; q[0] = fmaf(v0, v0, q[0]);
        s[1] += v1; q[1] = fmaf(v1, v1, q[1]);
        s[2] += v2; q[2] = fmaf(v2, v2, q[2]);
        s[3] += v3; q[3] = fmaf(v3, v3, q[3]);
        s[4] += v4; q[4] = fmaf(v4, v4, q[4]);
        s[5] += v5; q[5] = fmaf(v5, v5, q[5]);
        s[6] += v6; q[6] = fmaf(v6, v6, q[6]);
        s[7] += v7; q[7] = fmaf(v7, v7, q[7]);
    }
    int base = 72 * e0 + c8 * 8;
    *(float4*)(sPart + base)     = make_float4(s[0], s[1], s[2], s[3]);
    *(float4*)(sPart + base + 4) = make_float4(s[4], s[5], s[6], s[7]);
    *(float4*)(qPart + base)     = make_float4(q[0], q[1], q[2], q[3]);
    *(float4*)(qPart + base + 4) = make_float4(q[4], q[5], q[6], q[7]);
}

// -------------------- fp32 channel-strided stats (H side) --------------------
__global__ __launch_bounds__(256) void k_stats(
    const float* __restrict__ src, float* __restrict__ sPart,
    float* __restrict__ qPart, int iters)
{
    int tid = blockIdx.x * 256 + threadIdx.x;   // < 147456
    float s0 = 0.f, q0 = 0.f;
    size_t idx = tid;
    for (int it = 0; it < iters; ++it, idx += NSTAT_T) {
        float v = src[idx];
        s0 += v; q0 = fmaf(v, v, q0);
    }
    sPart[tid] = s0;
    qPart[tid] = q0;
}

// -------------------- stage-1 reduction: 2048 -> 64 partials per channel --------------
__global__ __launch_bounds__(256) void k_red(
    const float* __restrict__ sPart, const float* __restrict__ qPart,
    float* __restrict__ sRed, float* __restrict__ qRed)
{
    int tid = blockIdx.x * 256 + threadIdx.x;   // < 4608 (18 blocks)
    if (tid >= 4608) return;
    int g = tid / 72, c = tid - g * 72;         // g: 0..63
    int k0 = g * 32;
    float s0 = 0.f, s1 = 0.f, q0 = 0.f, q1 = 0.f;
#pragma unroll 4
    for (int k = 0; k < 32; k += 2) {
        s0 += sPart[c + 72 * (k0 + k)];
        s1 += sPart[c + 72 * (k0 + k + 1)];
        q0 += qPart[c + 72 * (k0 + k)];
        q1 += qPart[c + 72 * (k0 + k + 1)];
    }
    sRed[c + 72 * g] = s0 + s1;
    qRed[c + 72 * g] = q0 + q1;
}

// -------------------- BN finalize from 64 partials/channel --------------------
__global__ void k_fin2c(const float* __restrict__ sRed, const float* __restrict__ qRed,
                        const float* __restrict__ g, const float* __restrict__ be,
                        float* __restrict__ A, float* __restrict__ Bv, float Minv)
{
    __shared__ float ss[288], qs[288];
    int t = threadIdx.x;            // 288 threads
    int c = t % 72, qq = t / 72;
    float s = 0.f, q = 0.f;
    for (int k = qq; k < 64; k += 4) {
        s += sRed[c + 72 * k];
        q += qRed[c + 72 * k];
    }
    ss[t] = s; qs[t] = q;
    __syncthreads();
    if (t < 72) {
        s = ss[t] + ss[t + 72] + ss[t + 144] + ss[t + 216];
        q = qs[t] + qs[t + 72] + qs[t + 144] + qs[t + 216];
        float mu = s * Minv;
        float var = q * Minv - mu * mu;
        float inv = rsqrtf(var + EPS_);
        float a = g[t] * inv;
        A[t] = a;
        Bv[t] = be[t] - mu * a;
    }
}

// ---- e2f: fused bf16-z->BN->GEMM2->gate->m + LDS-transpose + GEMM3 ----
__global__ __launch_bounds__(256) void k_e2f(
    const float* __restrict__ x,
    const int* __restrict__ ei, const int* __restrict__ ej,
    const float* __restrict__ We2, const float* __restrict__ be2,
    const float* __restrict__ Wm, const float* __restrict__ bm,
    const float* __restrict__ bx1, const float* __restrict__ Wx1,
    const float* __restrict__ Wx2,
    const float* __restrict__ Ae, const float* __restrict__ Be,
    const unsigned short* zG, float* mz, float* __restrict__ agg)
{
    __shared__ short W2S[80 * 104];
    __shared__ short WxS[80 * 104];
    __shared__ short mS[4][16 * MSTR];
    __shared__ float lagg[128 * 5];
    int t = threadIdx.x;
    for (int idx = t; idx < 128 * 5; idx += 256) lagg[idx] = 0.f;
    for (int idx = t; idx < 80 * 104; idx += 256) {
        int n = idx / 104, k = idx - n * 104;
        bool v = (n < 72 && k < 72);
        W2S[idx] = f2bf(v ? We2[k * 72 + n] : 0.f);
        WxS[idx] = f2bf(v ? Wx1[k * 72 + n] : 0.f);
    }
    __syncthreads();

    int base = blockIdx.x * 256;          // 2048 blocks x 256 edges
    int b = base >> 14;
    int w = t >> 6, l = t & 63, ln = l & 15, g4 = l >> 4;
    float bm0 = bm[0];

    float4 a00 = *(const float4*)(Ae + g4 * 8),      a01 = *(const float4*)(Ae + g4 * 8 + 4);
    float4 b00 = *(const float4*)(Be + g4 * 8),      b01 = *(const float4*)(Be + g4 * 8 + 4);
    float4 a10 = *(const float4*)(Ae + 32 + g4 * 8), a11 = *(const float4*)(Ae + 32 + g4 * 8 + 4);
    float4 b10 = *(const float4*)(Be + 32 + g4 * 8), b11 = *(const float4*)(Be + 32 + g4 * 8 + 4);
    float4 a20, a21, b20, b21;
    if (g4 == 0) {
        a20 = *(const float4*)(Ae + 64); a21 = *(const float4*)(Ae + 68);
        b20 = *(const float4*)(Be + 64); b21 = *(const float4*)(Be + 68);
    } else {
        a20 = make_float4(0, 0, 0, 0); a21 = a20; b20 = a20; b21 = a20;
    }
    float be2v[5], wmv[5], bxv[5], wxv[5];
#pragma unroll
    for (int nt = 0; nt < 5; ++nt) {
        int chan = nt * 16 + ln;
        bool cv = chan < 72;
        be2v[nt] = cv ? be2[chan] : 0.f;
        wmv[nt]  = cv ? Wm[chan]  : 0.f;
        bxv[nt]  = cv ? bx1[chan] : 0.f;
        wxv[nt]  = cv ? Wx2[chan] : 0.f;
    }
    const short8v zero8 = {0, 0, 0, 0, 0, 0, 0, 0};
    {
#pragma unroll
        for (int q = 0; q < 4; ++q)
            mS[w][(l & 15) * MSTR + 72 + ((l >> 4) & 3) * 4 + q] = 0;
    }

    for (int ts = 0; ts < 4; ++ts) {
        int es = base + w * 64 + ts * 16;
        // ---- phase A: bf16 z -> BN -> GEMM2 -> gate ----
        const unsigned short* zrow = zG + (size_t)(es + ln) * 144;
        uint4 u0 = *(const uint4*)(zrow + g4 * 8);
        uint4 u1 = *(const uint4*)(zrow + 32 + g4 * 8);

        short8v az0, az1, az2 = zero8;
        az0[0] = f2bf(fmaxf(fmaf(b2f_lo(u0.x), a00.x, b00.x), 0.f));
        az0[1] = f2bf(fmaxf(fmaf(b2f_hi(u0.x), a00.y, b00.y), 0.f));
        az0[2] = f2bf(fmaxf(fmaf(b2f_lo(u0.y), a00.z, b00.z), 0.f));
        az0[3] = f2bf(fmaxf(fmaf(b2f_hi(u0.y), a00.w, b00.w), 0.f));
        az0[4] = f2bf(fmaxf(fmaf(b2f_lo(u0.z), a01.x, b01.x), 0.f));
        az0[5] = f2bf(fmaxf(fmaf(b2f_hi(u0.z), a01.y, b01.y), 0.f));
        az0[6] = f2bf(fmaxf(fmaf(b2f_lo(u0.w), a01.z, b01.z), 0.f));
        az0[7] = f2bf(fmaxf(fmaf(b2f_hi(u0.w), a01.w, b01.w), 0.f));
        az1[0] = f2bf(fmaxf(fmaf(b2f_lo(u1.x), a10.x, b10.x), 0.f));
        az1[1] = f2bf(fmaxf(fmaf(b2f_hi(u1.x), a10.y, b10.y), 0.f));
        az1[2] = f2bf(fmaxf(fmaf(b2f_lo(u1.y), a10.z, b10.z), 0.f));
        az1[3] = f2bf(fmaxf(fmaf(b2f_hi(u1.y), a10.w, b10.w), 0.f));
        az1[4] = f2bf(fmaxf(fmaf(b2f_lo(u1.z), a11.x, b11.x), 0.f));
        az1[5] = f2bf(fmaxf(fmaf(b2f_hi(u1.z), a11.y, b11.y), 0.f));
        az1[6] = f2bf(fmaxf(fmaf(b2f_lo(u1.w), a11.z, b11.z), 0.f));
        az1[7] = f2bf(fmaxf(fmaf(b2f_hi(u1.w), a11.w, b11.w), 0.f));
        if (g4 == 0) {
            uint4 u2 = *(const uint4*)(zrow + 64);
            az2[0] = f2bf(fmaxf(fmaf(b2f_lo(u2.x), a20.x, b20.x), 0.f));
            az2[1] = f2bf(fmaxf(fmaf(b2f_hi(u2.x), a20.y, b20.y), 0.f));
            az2[2] = f2bf(fmaxf(fmaf(b2f_lo(u2.y), a20.z, b20.z), 0.f));
            az2[3] = f2bf(fmaxf(fmaf(b2f_hi(u2.y), a20.w, b20.w), 0.f));
            az2[4] = f2bf(fmaxf(fmaf(b2f_lo(u2.z), a21.x, b21.x), 0.f));
            az2[5] = f2bf(fmaxf(fmaf(b2f_hi(u2.z), a21.y, b21.y), 0.f));
            az2[6] = f2bf(fmaxf(fmaf(b2f_lo(u2.w), a21.z, b21.z), 0.f));
            az2[7] = f2bf(fmaxf(fmaf(b2f_hi(u2.w), a21.w, b21.w), 0.f));
        }

        f32x4v acc[5];
#pragma unroll
        for (int nt = 0; nt < 5; ++nt) { f32x4v zz = {0.f, 0.f, 0.f, 0.f}; acc[nt] = zz; }
#pragma unroll
        for (int nt = 0; nt < 5; ++nt) {
            int rb = (nt * 16 + ln) * 104 + g4 * 8;
            short8v bw0 = *(const short8v*)&W2S[rb];
            short8v bw1 = *(const short8v*)&W2S[rb + 32];
            short8v bw2 = *(const short8v*)&W2S[rb + 64];
            acc[nt] = __builtin_amdgcn_mfma_f32_16x16x32_bf16(az0, bw0, acc[nt], 0, 0, 0);
            acc[nt] = __builtin_amdgcn_mfma_f32_16x16x32_bf16(az1, bw1, acc[nt], 0, 0, 0);
            acc[nt] = __builtin_amdgcn_mfma_f32_16x16x32_bf16(az2, bw2, acc[nt], 0, 0, 0);
        }

        float mt[5][4];
        float wdot[4] = {bm0, bm0, bm0, bm0};
#pragma unroll
        for (int nt = 0; nt < 5; ++nt) {
#pragma unroll
            for (int r = 0; r < 4; ++r) {
                mt[nt][r] = fmaxf(acc[nt][r] + be2v[nt], 0.f);
                wdot[r] = fmaf(mt[nt][r], wmv[nt], wdot[r]);
            }
        }
#pragma unroll
        for (int r = 0; r < 4; ++r) {
            wdot[r] += __shfl_xor(wdot[r], 1);
            wdot[r] += __shfl_xor(wdot[r], 2);
            wdot[r] += __shfl_xor(wdot[r], 4);
            wdot[r] += __shfl_xor(wdot[r], 8);
            wdot[r] = 1.f / (1.f + expf(-wdot[r]));
        }
        // m store (global fp32) + mS (bf16)
#pragma unroll
        for (int nt = 0; nt < 5; ++nt) {
            int chan = nt * 16 + ln;
#pragma unroll
            for (int r = 0; r < 4; ++r) {
                float mv = mt[nt][r] * wdot[r];
                mS[w][(g4 * 4 + r) * MSTR + chan] = f2bf(mv);
                if (chan < 72)
                    mz[(size_t)(es + g4 * 4 + r) * 72 + chan] = mv;
            }
        }
        __syncthreads();

        // ---- phase B: GEMM3 from mS ----
        short8v am0 = *(const short8v*)&mS[w][ln * MSTR + g4 * 8];
        short8v am1 = *(const short8v*)&mS[w][ln * MSTR + 32 + g4 * 8];
        short8v am2 = zero8;
        if (g4 == 0) am2 = *(const short8v*)&mS[w][ln * MSTR + 64];

        f32x4v acc3[5];
#pragma unroll
        for (int nt = 0; nt < 5; ++nt) { f32x4v zz = {0.f, 0.f, 0.f, 0.f}; acc3[nt] = zz; }
#pragma unroll
        for (int nt = 0; nt < 5; ++nt) {
            int rb = (nt * 16 + ln) * 104 + g4 * 8;
            short8v bw0 = *(const short8v*)&WxS[rb];
            short8v bw1 = *(const short8v*)&WxS[rb + 32];
            short8v bw2 = *(const short8v*)&WxS[rb + 64];
            acc3[nt] = __builtin_amdgcn_mfma_f32_16x16x32_bf16(am0, bw0, acc3[nt], 0, 0, 0);
            acc3[nt] = __builtin_amdgcn_mfma_f32_16x16x32_bf16(am1, bw1, acc3[nt], 0, 0, 0);
            acc3[nt] = __builtin_amdgcn_mfma_f32_16x16x32_bf16(am2, bw2, acc3[nt], 0, 0, 0);
        }

        float ph[4] = {0.f, 0.f, 0.f, 0.f};
#pragma unroll
        for (int nt = 0; nt < 5; ++nt) {
#pragma unroll
            for (int r = 0; r < 4; ++r)
                ph[r] = fmaf(fmaxf(acc3[nt][r] + bxv[nt], 0.f), wxv[nt], ph[r]);
        }
#pragma unroll
        for (int r = 0; r < 4; ++r) {
            ph[r] += __shfl_xor(ph[r], 1);
            ph[r] += __shfl_xor(ph[r], 2);
            ph[r] += __shfl_xor(ph[r], 4);
            ph[r] += __shfl_xor(ph[r], 8);
        }
        if (ln == 0) {
#pragma unroll
            for (int r = 0; r < 4; ++r) {
                int eg = es + g4 * 4 + r;
                int ii = ei[eg], jj = ej[eg];
                float4 xi = *(const float4*)(x + (size_t)(b * N_ + ii) * 4);
                float4 xj = *(const float4*)(x + (size_t)(b * N_ + jj) * 4);
                float phx = ph[r];
                float trx = fminf(fmaxf((xi.x - xj.x) * phx, -100.f), 100.f);
                float try_ = fminf(fmaxf((xi.y - xj.y) * phx, -100.f), 100.f);
                float trz = fminf(fmaxf((xi.z - xj.z) * phx, -100.f), 100.f);
                float trw = fminf(fmaxf((xi.w - xj.w) * phx, -100.f), 100.f);
                FADD(&lagg[ii * 5 + 0], trx);
                FADD(&lagg[ii * 5 + 1], try_);
                FADD(&lagg[ii * 5 + 2], trz);
                FADD(&lagg[ii * 5 + 3], trw);
            }
        }
        __syncthreads();
    }

    int nb = b * N_;
    for (int idx = t; idx < 128 * 4; idx += 256) {
        int n = idx >> 2, d = idx & 3;
        float v = lagg[n * 5 + d];
        if (v != 0.f) FADD(&agg[(nb + n) * 4 + d], v);
    }
}

// ---- k_seg2: float4 gather segment sum (thread = node x 4-chan group) ----
__global__ __launch_bounds__(256) void k_seg2(
    const float* __restrict__ m, const unsigned short* __restrict__ perm,
    const int* __restrict__ offs, const int* __restrict__ hist,
    float* __restrict__ magg)
{
    int tid = blockIdx.x * 256 + threadIdx.x;   // < 73728 (288 blocks)
    int g = tid / 18, c4 = tid - g * 18;        // g: node 0..4095, c4: 0..17
    int b = g >> 7;
    int start = offs[g];
    int count = hist[g];
    const unsigned short* p = perm + (size_t)b * E_ + start;
    const float* mb = m + (size_t)b * E_ * 72 + c4 * 4;
    float4 a0 = make_float4(0.f, 0.f, 0.f, 0.f);
    float4 a1 = make_float4(0.f, 0.f, 0.f, 0.f);
    int k = 0;
    for (; k + 1 < count; k += 2) {
        float4 v0 = *(const float4*)(mb + (size_t)p[k] * 72);
        float4 v1 = *(const float4*)(mb + (size_t)p[k + 1] * 72);
        a0.x += v0.x; a0.y += v0.y; a0.z += v0.z; a0.w += v0.w;
        a1.x += v1.x; a1.y += v1.y; a1.z += v1.z; a1.w += v1.w;
    }
    if (k < count) {
        float4 v0 = *(const float4*)(mb + (size_t)p[k] * 72);
        a0.x += v0.x; a0.y += v0.y; a0.z += v0.z; a0.w += v0.w;
    }
    *(float4*)(magg + (size_t)g * 72 + c4 * 4) =
        make_float4(a0.x + a1.x, a0.y + a1.y, a0.z + a1.z, a0.w + a1.w);
}

// -------------------- node1 (x8 channel split) --------------------
__global__ __launch_bounds__(256) void k_node1v3(
    const float* __restrict__ h, const float* __restrict__ magg,
    const float* __restrict__ attr, const float* __restrict__ Wh1,
    const float* __restrict__ bh1, float* __restrict__ zh1)
{
    int blk = blockIdx.x;                  // 128
    int q = blk >> 4;                      // 0..7
    int row = (blk & 15) * 256 + threadIdx.x;   // < 4096
    int c0 = q * 9;
    float acc[9];
#pragma unroll
    for (int c = 0; c < 9; ++c) acc[c] = bh1[c0 + c];

    const float4* h4 = (const float4*)(h + (size_t)row * 72);
    for (int kc = 0; kc < 18; ++kc) {
        float4 a = h4[kc];
        const float* wr = Wh1 + (kc * 4) * 72 + c0;
#pragma unroll
        for (int c = 0; c < 9; ++c)
            acc[c] = fmaf(a.x, wr[c], fmaf(a.y, wr[72 + c], fmaf(a.z, wr[144 + c], fmaf(a.w, wr[216 + c], acc[c]))));
    }
    const float4* mg4 = (const float4*)(magg + (size_t)row * 72);
    for (int kc = 0; kc < 18; ++kc) {
        float4 a = mg4[kc];
        const float* wr = Wh1 + (72 + kc * 4) * 72 + c0;
#pragma unroll
        for (int c = 0; c < 9; ++c)
            acc[c] = fmaf(a.x, wr[c], fmaf(a.y, wr[72 + c], fmaf(a.z, wr[144 + c], fmaf(a.w, wr[216 + c], acc[c]))));
    }
    const float4* at4 = (const float4*)(attr + (size_t)row * 8);
    for (int kc = 0; kc < 2; ++kc) {
        float4 a = at4[kc];
        const float* wr = Wh1 + (144 + kc * 4) * 72 + c0;
#pragma unroll
        for (int c = 0; c < 9; ++c)
            acc[c] = fmaf(a.x, wr[c], fmaf(a.y, wr[72 + c], fmaf(a.z, wr[144 + c], fmaf(a.w, wr[216 + c], acc[c]))));
    }
    float* zr = zh1 + (size_t)row * 72 + c0;
#pragma unroll
    for (int c = 0; c < 9; ++c) zr[c] = acc[c];
}

// -------------------- node2 (x8 channel split) --------------------
__global__ __launch_bounds__(256) void k_node2v2(
    const float* __restrict__ h, const float* __restrict__ x,
    const float* __restrict__ zh1,
    const float* __restrict__ Ah, const float* __restrict__ Bh,
    const float* __restrict__ Wh2, const float* __restrict__ bh2,
    const float* __restrict__ agg, const float* __restrict__ cnt,
    float* __restrict__ hout, float* __restrict__ xout)
{
    int blk = blockIdx.x;                  // 128
    int q = blk >> 4;                      // 0..7
    int row = (blk & 15) * 256 + threadIdx.x;   // < 4096
    int c0 = q * 9;
    float acc[9];
#pragma unroll
    for (int c = 0; c < 9; ++c) acc[c] = bh2[c0 + c];

    const float4* z4 = (const float4*)(zh1 + (size_t)row * 72);
    for (int kc = 0; kc < 18; ++kc) {
        float4 v = z4[kc];
        int k0 = kc * 4;
        float z0 = fmaxf(fmaf(v.x, Ah[k0],     Bh[k0]),     0.f);
        float z1v = fmaxf(fmaf(v.y, Ah[k0 + 1], Bh[k0 + 1]), 0.f);
        float z2v = fmaxf(fmaf(v.z, Ah[k0 + 2], Bh[k0 + 2]), 0.f);
        float z3v = fmaxf(fmaf(v.w, Ah[k0 + 3], Bh[k0 + 3]), 0.f);
        const float* w0 = Wh2 + k0 * 72 + c0;
#pragma unroll
        for (int c = 0; c < 9; ++c)
            acc[c] = fmaf(z0, w0[c], fmaf(z1v, w0[72 + c], fmaf(z2v, w0[144 + c], fmaf(z3v, w0[216 + c], acc[c]))));
    }
    const float* hr = h + (size_t)row * 72 + c0;
    float* ho = hout + (size_t)row * 72 + c0;
#pragma unroll
    for (int c = 0; c < 9; ++c) ho[c] = hr[c] + acc[c];

    if (q == 0) {
        float inv = 1.f / fmaxf(cnt[row], 1.f);
        float4 xv = *(const float4*)(x + (size_t)row * 4);
        float4 av = *(const float4*)(agg + (size_t)row * 4);
        *(float4*)(xout + (size_t)row * 4) = make_float4(xv.x + av.x * inv, xv.y + av.y * inv,
                                                         xv.z + av.z * inv, xv.w + av.w * inv);
    }
}

extern "C" void kernel_launch(void* const* d_in, const int* in_sizes, int n_in,
                              void* d_out, int out_size, void* d_ws, size_t ws_size,
                              hipStream_t stream) {
    const float* h    = (const float*)d_in[0];
    const float* x    = (const float*)d_in[1];
    const int*   ei   = (const int*)d_in[2];
    const int*   ej   = (const int*)d_in[3];
    const float* attr = (const float*)d_in[4];
    const float* We1  = (const float*)d_in[5];
    const float* ge   = (const float*)d_in[6];
    const float* bee  = (const float*)d_in[7];
    const float* We2  = (const float*)d_in[8];
    const float* be2  = (const float*)d_in[9];
    const float* Wm   = (const float*)d_in[10];
    const float* bm   = (const float*)d_in[11];
    const float* Wx1  = (const float*)d_in[12];
    const float* bx1  = (const float*)d_in[13];
    const float* Wx2  = (const float*)d_in[14];
    const float* Wh1  = (const float*)d_in[15];
    const float* bh1  = (const float*)d_in[16];
    const float* gh   = (const float*)d_in[17];
    const float* beh  = (const float*)d_in[18];
    const float* Wh2  = (const float*)d_in[19];
    const float* bh2  = (const float*)d_in[20];

    float* out  = (float*)d_out;
    float* hout = out + HOUT_OFF;
    float* xout = out + XOUT_OFF;
    float* mz   = out + M_OFF;                        // z1 (bf16 in-slot), then m (fp32)
    unsigned short* zG = (unsigned short*)mz;
    float* ws   = (float*)d_ws;
    float* sRed = xout;
    float* qRed = xout + 4608;

    hipMemsetAsync(ws, 0, (size_t)WS_ZERO_END * 4, stream);
    hipMemsetAsync(ws + WS_HIST, 0, 4096 * 4, stream);
    k_nodeproj<<<128, 256, 0, stream>>>(h, We1, ws + WS_ZH1, ws + WS_MAGG);
    k_edge1v4<<<2048, 256, 0, stream>>>(x, ei, ej, ws + WS_ZH1, ws + WS_MAGG, We1,
                                        zG, (int*)(ws + WS_HIST));
    k_scan<<<32, 128, 0, stream>>>((const int*)(ws + WS_HIST), (int*)(ws + WS_OFFS),
                                   (int*)(ws + WS_CURS), ws + WS_CNT);
    k_scatter<<<2048, 256, 0, stream>>>(ei, (int*)(ws + WS_CURS),
                                        (unsigned short*)(ws + WS_PERM));
    k_stats_bf<<<72, 256, 0, stream>>>(zG, ws + WS_MAGG, ws + WS_MAGG + NSTAT_T);
    k_red<<<18, 256, 0, stream>>>(ws + WS_MAGG, ws + WS_MAGG + NSTAT_T, sRed, qRed);
    k_fin2c<<<1, 288, 0, stream>>>(sRed, qRed, ge, bee,
                                   ws + WS_AE, ws + WS_BE, 1.0f / (float)(B_ * E_));
    k_e2f<<<2048, 256, 0, stream>>>(x, ei, ej, We2, be2, Wm, bm, bx1, Wx1, Wx2,
                                    ws + WS_AE, ws + WS_BE, zG, mz, ws + WS_AGG);
    k_seg2<<<288, 256, 0, stream>>>(mz, (const unsigned short*)(ws + WS_PERM),
                                    (const int*)(ws + WS_OFFS), (const int*)(ws + WS_HIST),
                                    ws + WS_MAGG);
    k_node1v3<<<128, 256, 0, stream>>>(h, ws + WS_MAGG, attr, Wh1, bh1, ws + WS_ZH1);
    k_stats<<<576, 256, 0, stream>>>(ws + WS_ZH1, hout, hout + NSTAT_T, 2);
    k_red<<<18, 256, 0, stream>>>(hout, hout + NSTAT_T, sRed, qRed);
    k_fin2c<<<1, 288, 0, stream>>>(sRed, qRed, gh, beh,
                                   ws + WS_AH, ws + WS_BH, 1.0f / 4096.0f);
    k_node2v2<<<128, 256, 0, stream>>>(h, x, ws + WS_ZH1, ws + WS_AH, ws + WS_BH, Wh2, bh2,
                                       ws + WS_AGG, ws + WS_CNT, hout, xout);
}

// Round 22
// 328.741 us; speedup vs baseline: 1.0254x; 1.0254x over previous
//
#include <hip/hip_runtime.h>
#include <math.h>

#define B_ 32
#define N_ 128
#define E_ 16384
#define EPS_ 1e-5f

typedef short short8v __attribute__((ext_vector_type(8)));
typedef float f32x4v __attribute__((ext_vector_type(4)));

#define FADD(p, v) unsafeAtomicAdd((p), (v))

// ---- ws layout (float offsets): round-0 proven footprint ----
#define WS_MAGG    4608     // B*N*72  (Pmid, then stats partials, then magg)
#define WS_AGG     299520   // B*N*4
#define WS_CNT     315904   // B*N (float counts, written by k_scan)
#define WS_ZERO_END 320000
#define WS_AE      320000
#define WS_BE      320072
#define WS_AH      320144
#define WS_BH      320216
#define WS_HIST    320288   // int[4096] -- outside Ptop (r19 fix)
#define WS_ZH1     325472   // B*N*72: P_top, then {perm+tables}, then zh1
#define WS_PERM    325472   // ushort[B*E] (written after Ptop dies)
#define WS_OFFS    591712   // int[4096]  (written after Ptop dies)
#define WS_CURS    595808   // int[4096]  (end 599904 < 620384)

#define HOUT_OFF 0
#define XOUT_OFF 294912
#define M_OFF    311296

#define NSTAT_T 147456
#define MSTR 88            // mS row stride in shorts: 176B = 44 banks -> 2-way max

static __device__ __forceinline__ short f2bf(float f) {
    unsigned int u = __builtin_bit_cast(unsigned int, f);
    u += 0x7FFFu + ((u >> 16) & 1u);
    return (short)(u >> 16);
}
static __device__ __forceinline__ unsigned int pack2(float a, float b) {
    return (unsigned int)(unsigned short)f2bf(a) | ((unsigned int)(unsigned short)f2bf(b) << 16);
}
static __device__ __forceinline__ float b2f(unsigned short u) {
    return __builtin_bit_cast(float, (unsigned int)u << 16);
}
static __device__ __forceinline__ float b2f_lo(unsigned int u) {
    return __builtin_bit_cast(float, u << 16);
}
static __device__ __forceinline__ float b2f_hi(unsigned int u) {
    return __builtin_bit_cast(float, u & 0xFFFF0000u);
}

// ---- node projections (q/which block-uniform) ----
__global__ __launch_bounds__(256) void k_nodeproj(
    const float* __restrict__ h, const float* __restrict__ We1,
    float* __restrict__ Ptop, float* __restrict__ Pmid)
{
    int blk = blockIdx.x;                 // 128
    int rowBlk = blk >> 3, sub = blk & 7;
    int which = sub >> 2, q = sub & 3;
    int row = rowBlk * 256 + threadIdx.x; // < 4096
    int c0 = q * 18;
    const float4* h4 = (const float4*)(h + (size_t)row * 72);
    const float* base = We1 + which * 5184 + c0;
    float acc[18];
#pragma unroll
    for (int c = 0; c < 18; ++c) acc[c] = 0.f;
    for (int kc = 0; kc < 18; ++kc) {
        float4 a = h4[kc];
        const float* wr = base + (kc * 4) * 72;
#pragma unroll
        for (int c = 0; c < 18; ++c)
            acc[c] = fmaf(a.x, wr[c], fmaf(a.y, wr[72 + c], fmaf(a.z, wr[144 + c], fmaf(a.w, wr[216 + c], acc[c]))));
    }
    float* P = (which ? Pmid : Ptop) + (size_t)row * 72 + c0;
#pragma unroll
    for (int c = 0; c < 18; ++c) P[c] = acc[c];
}

// ---- edge pass 1: z1(bf16, 144B in each 288B m-slot) + per-block edge histogram ----
__global__ __launch_bounds__(256) void k_edge1v4(
    const float* __restrict__ x,
    const int* __restrict__ ei, const int* __restrict__ ej,
    const float* __restrict__ Ptop, const float* __restrict__ Pmid,
    const float* __restrict__ We1,
    unsigned short* __restrict__ zG, int* __restrict__ hist)
{
    __shared__ int lh[128];
    int t = threadIdx.x;
    if (t < 128) lh[t] = 0;
    __syncthreads();

    int eg = blockIdx.x * 256 + t;
    int b = eg >> 14;
    int i = ei[eg], j = ej[eg];
    atomicAdd(&lh[i], 1);
    int ri = b * N_ + i, rj = b * N_ + j;

    float4 xi = *(const float4*)(x + ri * 4);
    float4 xj = *(const float4*)(x + rj * 4);
    float xdx = xi.x - xj.x, xdy = xi.y - xj.y, xdz = xi.z - xj.z, xdw = xi.w - xj.w;
    float nsq = xdx * xdx - xdy * xdy - xdz * xdz - xdw * xdw;
    float dsq = xi.x * xj.x - xi.y * xj.y - xi.z * xj.z - xi.w * xj.w;
    float norms = copysignf(log1pf(fabsf(nsq)), nsq);
    float dots  = copysignf(log1pf(fabsf(dsq)), dsq);

    const float4* pt4 = (const float4*)(Ptop + (size_t)ri * 72);
    const float4* pm4 = (const float4*)(Pmid + (size_t)rj * 72);
    const float* w144 = We1 + 144 * 72;
    const float* w145 = We1 + 145 * 72;
    uint4* zr = (uint4*)(zG + (size_t)eg * 144);

#pragma unroll
    for (int g = 0; g < 9; ++g) {
        float4 a0 = pt4[2 * g],     bq0 = pm4[2 * g];
        float4 a1 = pt4[2 * g + 1], bq1 = pm4[2 * g + 1];
        float4 wa0 = *(const float4*)(w144 + 8 * g);
        float4 wb0 = *(const float4*)(w145 + 8 * g);
        float4 wa1 = *(const float4*)(w144 + 8 * g + 4);
        float4 wb1 = *(const float4*)(w145 + 8 * g + 4);
        float r0 = fmaf(norms, wa0.x, fmaf(dots, wb0.x, a0.x + bq0.x));
        float r1 = fmaf(norms, wa0.y, fmaf(dots, wb0.y, a0.y + bq0.y));
        float r2 = fmaf(norms, wa0.z, fmaf(dots, wb0.z, a0.z + bq0.z));
        float r3 = fmaf(norms, wa0.w, fmaf(dots, wb0.w, a0.w + bq0.w));
        float r4 = fmaf(norms, wa1.x, fmaf(dots, wb1.x, a1.x + bq1.x));
        float r5 = fmaf(norms, wa1.y, fmaf(dots, wb1.y, a1.y + bq1.y));
        float r6 = fmaf(norms, wa1.z, fmaf(dots, wb1.z, a1.z + bq1.z));
        float r7 = fmaf(norms, wa1.w, fmaf(dots, wb1.w, a1.w + bq1.w));
        uint4 u;
        u.x = pack2(r0, r1); u.y = pack2(r2, r3);
        u.z = pack2(r4, r5); u.w = pack2(r6, r7);
        zr[g] = u;
    }
    __syncthreads();
    if (t < 128) {
        int v = lh[t];
        if (v) atomicAdd(&hist[b * N_ + t], v);
    }
}

// -------------------- sort: scan / scatter --------------------
__global__ void k_scan(const int* __restrict__ hist, int* __restrict__ offs,
                       int* __restrict__ curs, float* __restrict__ cnt)
{
    __shared__ int sh[128];
    int b = blockIdx.x, n = threadIdx.x;  // 32 x 128
    int cv = hist[b * N_ + n];
    sh[n] = cv;
    __syncthreads();
    for (int off = 1; off < 128; off <<= 1) {
        int v = (n >= off) ? sh[n - off] : 0;
        __syncthreads();
        sh[n] += v;
        __syncthreads();
    }
    int excl = sh[n] - cv;
    offs[b * N_ + n] = excl;
    curs[b * N_ + n] = excl;
    cnt[b * N_ + n] = (float)cv;
}

__global__ __launch_bounds__(256) void k_scatter(
    const int* __restrict__ ei, int* __restrict__ curs,
    unsigned short* __restrict__ perm)
{
    int eg = blockIdx.x * 256 + threadIdx.x;  // < 524288
    int b = eg >> 14;
    int i = ei[eg];
    int pos = atomicAdd(&curs[b * N_ + i], 1);
    perm[(size_t)b * E_ + pos] = (unsigned short)(eg & (E_ - 1));
}

// -------------------- BN stats over bf16 z (padded 144-ushort rows) --------------------
__global__ __launch_bounds__(256) void k_stats_bf(
    const unsigned short* __restrict__ zG,
    float* __restrict__ sPart, float* __restrict__ qPart)
{
    int tid = blockIdx.x * 256 + threadIdx.x;   // < 147456
    int c = tid % 72, e0 = tid / 72;            // e0: 0..2047
    float s0 = 0.f, s1 = 0.f, s2 = 0.f, s3 = 0.f;
    float q0 = 0.f, q1 = 0.f, q2 = 0.f, q3 = 0.f;
    size_t idx = (size_t)e0 * 144 + c;
    const size_t step = (size_t)2048 * 144;
    for (int k = 0; k < 256; k += 4, idx += 4 * step) {
        float v0 = b2f(zG[idx]);
        float v1 = b2f(zG[idx + step]);
        float v2 = b2f(zG[idx + 2 * step]);
        float v3 = b2f(zG[idx + 3 * step]);
        s0 += v0; q0 = fmaf(v0, v0, q0);
        s1 += v1; q1 = fmaf(v1, v1, q1);
        s2 += v2; q2 = fmaf(v2, v2, q2);
        s3 += v3; q3 = fmaf(v3, v3, q3);
    }
    sPart[tid] = (s0 + s1) + (s2 + s3);
    qPart[tid] = (q0 + q1) + (q2 + q3);
}

// -------------------- fp32 channel-strided stats (H side) --------------------
__global__ __launch_bounds__(256) void k_stats(
    const float* __restrict__ src, float* __restrict__ sPart,
    float* __restrict__ qPart, int iters)
{
    int tid = blockIdx.x * 256 + threadIdx.x;   // < 147456
    float s0 = 0.f, q0 = 0.f;
    size_t idx = tid;
    for (int it = 0; it < iters; ++it, idx += NSTAT_T) {
        float v = src[idx];
        s0 += v; q0 = fmaf(v, v, q0);
    }
    sPart[tid] = s0;
    qPart[tid] = q0;
}

// -------------------- stage-1 reduction: 2048 -> 64 partials per channel --------------
__global__ __launch_bounds__(256) void k_red(
    const float* __restrict__ sPart, const float* __restrict__ qPart,
    float* __restrict__ sRed, float* __restrict__ qRed)
{
    int tid = blockIdx.x * 256 + threadIdx.x;   // < 4608 (18 blocks)
    if (tid >= 4608) return;
    int g = tid / 72, c = tid - g * 72;         // g: 0..63
    int k0 = g * 32;
    float s0 = 0.f, s1 = 0.f, q0 = 0.f, q1 = 0.f;
#pragma unroll 4
    for (int k = 0; k < 32; k += 2) {
        s0 += sPart[c + 72 * (k0 + k)];
        s1 += sPart[c + 72 * (k0 + k + 1)];
        q0 += qPart[c + 72 * (k0 + k)];
        q1 += qPart[c + 72 * (k0 + k + 1)];
    }
    sRed[c + 72 * g] = s0 + s1;
    qRed[c + 72 * g] = q0 + q1;
}

// -------------------- BN finalize from 64 partials/channel --------------------
__global__ void k_fin2c(const float* __restrict__ sRed, const float* __restrict__ qRed,
                        const float* __restrict__ g, const float* __restrict__ be,
                        float* __restrict__ A, float* __restrict__ Bv, float Minv)
{
    __shared__ float ss[288], qs[288];
    int t = threadIdx.x;            // 288 threads
    int c = t % 72, qq = t / 72;
    float s = 0.f, q = 0.f;
    for (int k = qq; k < 64; k += 4) {
        s += sRed[c + 72 * k];
        q += qRed[c + 72 * k];
    }
    ss[t] = s; qs[t] = q;
    __syncthreads();
    if (t < 72) {
        s = ss[t] + ss[t + 72] + ss[t + 144] + ss[t + 216];
        q = qs[t] + qs[t + 72] + qs[t + 144] + qs[t + 216];
        float mu = s * Minv;
        float var = q * Minv - mu * mu;
        float inv = rsqrtf(var + EPS_);
        float a = g[t] * inv;
        A[t] = a;
        Bv[t] = be[t] - mu * a;
    }
}

// ---- e2f: fused bf16-z->BN->GEMM2->gate->m + LDS-transpose + GEMM3 ----
__global__ __launch_bounds__(256) void k_e2f(
    const float* __restrict__ x,
    const int* __restrict__ ei, const int* __restrict__ ej,
    const float* __restrict__ We2, const float* __restrict__ be2,
    const float* __restrict__ Wm, const float* __restrict__ bm,
    const float* __restrict__ bx1, const float* __restrict__ Wx1,
    const float* __restrict__ Wx2,
    const float* __restrict__ Ae, const float* __restrict__ Be,
    const unsigned short* zG, float* mz, float* __restrict__ agg)
{
    __shared__ short W2S[80 * 104];
    __shared__ short WxS[80 * 104];
    __shared__ short mS[4][16 * MSTR];
    __shared__ float lagg[128 * 5];
    int t = threadIdx.x;
    for (int idx = t; idx < 128 * 5; idx += 256) lagg[idx] = 0.f;
    for (int idx = t; idx < 80 * 104; idx += 256) {
        int n = idx / 104, k = idx - n * 104;
        bool v = (n < 72 && k < 72);
        W2S[idx] = f2bf(v ? We2[k * 72 + n] : 0.f);
        WxS[idx] = f2bf(v ? Wx1[k * 72 + n] : 0.f);
    }
    __syncthreads();

    int base = blockIdx.x * 256;          // 2048 blocks x 256 edges
    int b = base >> 14;
    int w = t >> 6, l = t & 63, ln = l & 15, g4 = l >> 4;
    float bm0 = bm[0];

    float4 a00 = *(const float4*)(Ae + g4 * 8),      a01 = *(const float4*)(Ae + g4 * 8 + 4);
    float4 b00 = *(const float4*)(Be + g4 * 8),      b01 = *(const float4*)(Be + g4 * 8 + 4);
    float4 a10 = *(const float4*)(Ae + 32 + g4 * 8), a11 = *(const float4*)(Ae + 32 + g4 * 8 + 4);
    float4 b10 = *(const float4*)(Be + 32 + g4 * 8), b11 = *(const float4*)(Be + 32 + g4 * 8 + 4);
    float4 a20, a21, b20, b21;
    if (g4 == 0) {
        a20 = *(const float4*)(Ae + 64); a21 = *(const float4*)(Ae + 68);
        b20 = *(const float4*)(Be + 64); b21 = *(const float4*)(Be + 68);
    } else {
        a20 = make_float4(0, 0, 0, 0); a21 = a20; b20 = a20; b21 = a20;
    }
    float be2v[5], wmv[5], bxv[5], wxv[5];
#pragma unroll
    for (int nt = 0; nt < 5; ++nt) {
        int chan = nt * 16 + ln;
        bool cv = chan < 72;
        be2v[nt] = cv ? be2[chan] : 0.f;
        wmv[nt]  = cv ? Wm[chan]  : 0.f;
        bxv[nt]  = cv ? bx1[chan] : 0.f;
        wxv[nt]  = cv ? Wx2[chan] : 0.f;
    }
    const short8v zero8 = {0, 0, 0, 0, 0, 0, 0, 0};
    {
#pragma unroll
        for (int q = 0; q < 4; ++q)
            mS[w][(l & 15) * MSTR + 72 + ((l >> 4) & 3) * 4 + q] = 0;
    }

    for (int ts = 0; ts < 4; ++ts) {
        int es = base + w * 64 + ts * 16;
        // ---- phase A: bf16 z -> BN -> GEMM2 -> gate ----
        const unsigned short* zrow = zG + (size_t)(es + ln) * 144;
        uint4 u0 = *(const uint4*)(zrow + g4 * 8);
        uint4 u1 = *(const uint4*)(zrow + 32 + g4 * 8);

        short8v az0, az1, az2 = zero8;
        az0[0] = f2bf(fmaxf(fmaf(b2f_lo(u0.x), a00.x, b00.x), 0.f));
        az0[1] = f2bf(fmaxf(fmaf(b2f_hi(u0.x), a00.y, b00.y), 0.f));
        az0[2] = f2bf(fmaxf(fmaf(b2f_lo(u0.y), a00.z, b00.z), 0.f));
        az0[3] = f2bf(fmaxf(fmaf(b2f_hi(u0.y), a00.w, b00.w), 0.f));
        az0[4] = f2bf(fmaxf(fmaf(b2f_lo(u0.z), a01.x, b01.x), 0.f));
        az0[5] = f2bf(fmaxf(fmaf(b2f_hi(u0.z), a01.y, b01.y), 0.f));
        az0[6] = f2bf(fmaxf(fmaf(b2f_lo(u0.w), a01.z, b01.z), 0.f));
        az0[7] = f2bf(fmaxf(fmaf(b2f_hi(u0.w), a01.w, b01.w), 0.f));
        az1[0] = f2bf(fmaxf(fmaf(b2f_lo(u1.x), a10.x, b10.x), 0.f));
        az1[1] = f2bf(fmaxf(fmaf(b2f_hi(u1.x), a10.y, b10.y), 0.f));
        az1[2] = f2bf(fmaxf(fmaf(b2f_lo(u1.y), a10.z, b10.z), 0.f));
        az1[3] = f2bf(fmaxf(fmaf(b2f_hi(u1.y), a10.w, b10.w), 0.f));
        az1[4] = f2bf(fmaxf(fmaf(b2f_lo(u1.z), a11.x, b11.x), 0.f));
        az1[5] = f2bf(fmaxf(fmaf(b2f_hi(u1.z), a11.y, b11.y), 0.f));
        az1[6] = f2bf(fmaxf(fmaf(b2f_lo(u1.w), a11.z, b11.z), 0.f));
        az1[7] = f2bf(fmaxf(fmaf(b2f_hi(u1.w), a11.w, b11.w), 0.f));
        if (g4 == 0) {
            uint4 u2 = *(const uint4*)(zrow + 64);
            az2[0] = f2bf(fmaxf(fmaf(b2f_lo(u2.x), a20.x, b20.x), 0.f));
            az2[1] = f2bf(fmaxf(fmaf(b2f_hi(u2.x), a20.y, b20.y), 0.f));
            az2[2] = f2bf(fmaxf(fmaf(b2f_lo(u2.y), a20.z, b20.z), 0.f));
            az2[3] = f2bf(fmaxf(fmaf(b2f_hi(u2.y), a20.w, b20.w), 0.f));
            az2[4] = f2bf(fmaxf(fmaf(b2f_lo(u2.z), a21.x, b21.x), 0.f));
            az2[5] = f2bf(fmaxf(fmaf(b2f_hi(u2.z), a21.y, b21.y), 0.f));
            az2[6] = f2bf(fmaxf(fmaf(b2f_lo(u2.w), a21.z, b21.z), 0.f));
            az2[7] = f2bf(fmaxf(fmaf(b2f_hi(u2.w), a21.w, b21.w), 0.f));
        }

        f32x4v acc[5];
#pragma unroll
        for (int nt = 0; nt < 5; ++nt) { f32x4v zz = {0.f, 0.f, 0.f, 0.f}; acc[nt] = zz; }
#pragma unroll
        for (int nt = 0; nt < 5; ++nt) {
            int rb = (nt * 16 + ln) * 104 + g4 * 8;
            short8v bw0 = *(const short8v*)&W2S[rb];
            short8v bw1 = *(const short8v*)&W2S[rb + 32];
            short8v bw2 = *(const short8v*)&W2S[rb + 64];
            acc[nt] = __builtin_amdgcn_mfma_f32_16x16x32_bf16(az0, bw0, acc[nt], 0, 0, 0);
            acc[nt] = __builtin_amdgcn_mfma_f32_16x16x32_bf16(az1, bw1, acc[nt], 0, 0, 0);
            acc[nt] = __builtin_amdgcn_mfma_f32_16x16x32_bf16(az2, bw2, acc[nt], 0, 0, 0);
        }

        float mt[5][4];
        float wdot[4] = {bm0, bm0, bm0, bm0};
#pragma unroll
        for (int nt = 0; nt < 5; ++nt) {
#pragma unroll
            for (int r = 0; r < 4; ++r) {
                mt[nt][r] = fmaxf(acc[nt][r] + be2v[nt], 0.f);
                wdot[r] = fmaf(mt[nt][r], wmv[nt], wdot[r]);
            }
        }
#pragma unroll
        for (int r = 0; r < 4; ++r) {
            wdot[r] += __shfl_xor(wdot[r], 1);
            wdot[r] += __shfl_xor(wdot[r], 2);
            wdot[r] += __shfl_xor(wdot[r], 4);
            wdot[r] += __shfl_xor(wdot[r], 8);
            wdot[r] = 1.f / (1.f + expf(-wdot[r]));
        }
        // m store (global fp32) + mS (bf16)
#pragma unroll
        for (int nt = 0; nt < 5; ++nt) {
            int chan = nt * 16 + ln;
#pragma unroll
            for (int r = 0; r < 4; ++r) {
                float mv = mt[nt][r] * wdot[r];
                mS[w][(g4 * 4 + r) * MSTR + chan] = f2bf(mv);
                if (chan < 72)
                    mz[(size_t)(es + g4 * 4 + r) * 72 + chan] = mv;
            }
        }
        __syncthreads();

        // ---- phase B: GEMM3 from mS ----
        short8v am0 = *(const short8v*)&mS[w][ln * MSTR + g4 * 8];
        short8v am1 = *(const short8v*)&mS[w][ln * MSTR + 32 + g4 * 8];
        short8v am2 = zero8;
        if (g4 == 0) am2 = *(const short8v*)&mS[w][ln * MSTR + 64];

        f32x4v acc3[5];
#pragma unroll
        for (int nt = 0; nt < 5; ++nt) { f32x4v zz = {0.f, 0.f, 0.f, 0.f}; acc3[nt] = zz; }
#pragma unroll
        for (int nt = 0; nt < 5; ++nt) {
            int rb = (nt * 16 + ln) * 104 + g4 * 8;
            short8v bw0 = *(const short8v*)&WxS[rb];
            short8v bw1 = *(const short8v*)&WxS[rb + 32];
            short8v bw2 = *(const short8v*)&WxS[rb + 64];
            acc3[nt] = __builtin_amdgcn_mfma_f32_16x16x32_bf16(am0, bw0, acc3[nt], 0, 0, 0);
            acc3[nt] = __builtin_amdgcn_mfma_f32_16x16x32_bf16(am1, bw1, acc3[nt], 0, 0, 0);
            acc3[nt] = __builtin_amdgcn_mfma_f32_16x16x32_bf16(am2, bw2, acc3[nt], 0, 0, 0);
        }

        float ph[4] = {0.f, 0.f, 0.f, 0.f};
#pragma unroll
        for (int nt = 0; nt < 5; ++nt) {
#pragma unroll
            for (int r = 0; r < 4; ++r)
                ph[r] = fmaf(fmaxf(acc3[nt][r] + bxv[nt], 0.f), wxv[nt], ph[r]);
        }
#pragma unroll
        for (int r = 0; r < 4; ++r) {
            ph[r] += __shfl_xor(ph[r], 1);
            ph[r] += __shfl_xor(ph[r], 2);
            ph[r] += __shfl_xor(ph[r], 4);
            ph[r] += __shfl_xor(ph[r], 8);
        }
        if (ln == 0) {
#pragma unroll
            for (int r = 0; r < 4; ++r) {
                int eg = es + g4 * 4 + r;
                int ii = ei[eg], jj = ej[eg];
                float4 xi = *(const float4*)(x + (size_t)(b * N_ + ii) * 4);
                float4 xj = *(const float4*)(x + (size_t)(b * N_ + jj) * 4);
                float phx = ph[r];
                float trx = fminf(fmaxf((xi.x - xj.x) * phx, -100.f), 100.f);
                float try_ = fminf(fmaxf((xi.y - xj.y) * phx, -100.f), 100.f);
                float trz = fminf(fmaxf((xi.z - xj.z) * phx, -100.f), 100.f);
                float trw = fminf(fmaxf((xi.w - xj.w) * phx, -100.f), 100.f);
                FADD(&lagg[ii * 5 + 0], trx);
                FADD(&lagg[ii * 5 + 1], try_);
                FADD(&lagg[ii * 5 + 2], trz);
                FADD(&lagg[ii * 5 + 3], trw);
            }
        }
        __syncthreads();
    }

    int nb = b * N_;
    for (int idx = t; idx < 128 * 4; idx += 256) {
        int n = idx >> 2, d = idx & 3;
        float v = lagg[n * 5 + d];
        if (v != 0.f) FADD(&agg[(nb + n) * 4 + d], v);
    }
}

// -------------------- k_seg2: gather-style segment sum (no atomics) --------------------
__global__ __launch_bounds__(256) void k_seg2(
    const float* __restrict__ m, const unsigned short* __restrict__ perm,
    const int* __restrict__ offs, const int* __restrict__ hist,
    float* __restrict__ magg)
{
    int tid = blockIdx.x * 256 + threadIdx.x;   // < 294912 (1152 blocks)
    int g = tid / 72, c = tid - g * 72;         // g: global node 0..4095
    int b = g >> 7;
    int start = offs[g];
    int count = hist[g];
    const unsigned short* p = perm + (size_t)b * E_ + start;
    const float* mb = m + (size_t)b * E_ * 72 + c;
    float a0 = 0.f, a1 = 0.f;
    int k = 0;
    for (; k + 1 < count; k += 2) {
        int e0 = p[k], e1 = p[k + 1];
        a0 += mb[(size_t)e0 * 72];
        a1 += mb[(size_t)e1 * 72];
    }
    if (k < count) a0 += mb[(size_t)p[k] * 72];
    magg[(size_t)g * 72 + c] = a0 + a1;
}

// -------------------- node1 (x8 channel split) --------------------
__global__ __launch_bounds__(256) void k_node1v3(
    const float* __restrict__ h, const float* __restrict__ magg,
    const float* __restrict__ attr, const float* __restrict__ Wh1,
    const float* __restrict__ bh1, float* __restrict__ zh1)
{
    int blk = blockIdx.x;                  // 128
    int q = blk >> 4;                      // 0..7
    int row = (blk & 15) * 256 + threadIdx.x;   // < 4096
    int c0 = q * 9;
    float acc[9];
#pragma unroll
    for (int c = 0; c < 9; ++c) acc[c] = bh1[c0 + c];

    const float4* h4 = (const float4*)(h + (size_t)row * 72);
    for (int kc = 0; kc < 18; ++kc) {
        float4 a = h4[kc];
        const float* wr = Wh1 + (kc * 4) * 72 + c0;
#pragma unroll
        for (int c = 0; c < 9; ++c)
            acc[c] = fmaf(a.x, wr[c], fmaf(a.y, wr[72 + c], fmaf(a.z, wr[144 + c], fmaf(a.w, wr[216 + c], acc[c]))));
    }
    const float4* mg4 = (const float4*)(magg + (size_t)row * 72);
    for (int kc = 0; kc < 18; ++kc) {
        float4 a = mg4[kc];
        const float* wr = Wh1 + (72 + kc * 4) * 72 + c0;
#pragma unroll
        for (int c = 0; c < 9; ++c)
            acc[c] = fmaf(a.x, wr[c], fmaf(a.y, wr[72 + c], fmaf(a.z, wr[144 + c], fmaf(a.w, wr[216 + c], acc[c]))));
    }
    const float4* at4 = (const float4*)(attr + (size_t)row * 8);
    for (int kc = 0; kc < 2; ++kc) {
        float4 a = at4[kc];
        const float* wr = Wh1 + (144 + kc * 4) * 72 + c0;
#pragma unroll
        for (int c = 0; c < 9; ++c)
            acc[c] = fmaf(a.x, wr[c], fmaf(a.y, wr[72 + c], fmaf(a.z, wr[144 + c], fmaf(a.w, wr[216 + c], acc[c]))));
    }
    float* zr = zh1 + (size_t)row * 72 + c0;
#pragma unroll
    for (int c = 0; c < 9; ++c) zr[c] = acc[c];
}

// -------------------- node2 (x8 channel split) --------------------
__global__ __launch_bounds__(256) void k_node2v2(
    const float* __restrict__ h, const float* __restrict__ x,
    const float* __restrict__ zh1,
    const float* __restrict__ Ah, const float* __restrict__ Bh,
    const float* __restrict__ Wh2, const float* __restrict__ bh2,
    const float* __restrict__ agg, const float* __restrict__ cnt,
    float* __restrict__ hout, float* __restrict__ xout)
{
    int blk = blockIdx.x;                  // 128
    int q = blk >> 4;                      // 0..7
    int row = (blk & 15) * 256 + threadIdx.x;   // < 4096
    int c0 = q * 9;
    float acc[9];
#pragma unroll
    for (int c = 0; c < 9; ++c) acc[c] = bh2[c0 + c];

    const float4* z4 = (const float4*)(zh1 + (size_t)row * 72);
    for (int kc = 0; kc < 18; ++kc) {
        float4 v = z4[kc];
        int k0 = kc * 4;
        float z0 = fmaxf(fmaf(v.x, Ah[k0],     Bh[k0]),     0.f);
        float z1v = fmaxf(fmaf(v.y, Ah[k0 + 1], Bh[k0 + 1]), 0.f);
        float z2v = fmaxf(fmaf(v.z, Ah[k0 + 2], Bh[k0 + 2]), 0.f);
        float z3v = fmaxf(fmaf(v.w, Ah[k0 + 3], Bh[k0 + 3]), 0.f);
        const float* w0 = Wh2 + k0 * 72 + c0;
#pragma unroll
        for (int c = 0; c < 9; ++c)
            acc[c] = fmaf(z0, w0[c], fmaf(z1v, w0[72 + c], fmaf(z2v, w0[144 + c], fmaf(z3v, w0[216 + c], acc[c]))));
    }
    const float* hr = h + (size_t)row * 72 + c0;
    float* ho = hout + (size_t)row * 72 + c0;
#pragma unroll
    for (int c = 0; c < 9; ++c) ho[c] = hr[c] + acc[c];

    if (q == 0) {
        float inv = 1.f / fmaxf(cnt[row], 1.f);
        float4 xv = *(const float4*)(x + (size_t)row * 4);
        float4 av = *(const float4*)(agg + (size_t)row * 4);
        *(float4*)(xout + (size_t)row * 4) = make_float4(xv.x + av.x * inv, xv.y + av.y * inv,
                                                         xv.z + av.z * inv, xv.w + av.w * inv);
    }
}

extern "C" void kernel_launch(void* const* d_in, const int* in_sizes, int n_in,
                              void* d_out, int out_size, void* d_ws, size_t ws_size,
                              hipStream_t stream) {
    const float* h    = (const float*)d_in[0];
    const float* x    = (const float*)d_in[1];
    const int*   ei   = (const int*)d_in[2];
    const int*   ej   = (const int*)d_in[3];
    const float* attr = (const float*)d_in[4];
    const float* We1  = (const float*)d_in[5];
    const float* ge   = (const float*)d_in[6];
    const float* bee  = (const float*)d_in[7];
    const float* We2  = (const float*)d_in[8];
    const float* be2  = (const float*)d_in[9];
    const float* Wm   = (const float*)d_in[10];
    const float* bm   = (const float*)d_in[11];
    const float* Wx1  = (const float*)d_in[12];
    const float* bx1  = (const float*)d_in[13];
    const float* Wx2  = (const float*)d_in[14];
    const float* Wh1  = (const float*)d_in[15];
    const float* bh1  = (const float*)d_in[16];
    const float* gh   = (const float*)d_in[17];
    const float* beh  = (const float*)d_in[18];
    const float* Wh2  = (const float*)d_in[19];
    const float* bh2  = (const float*)d_in[20];

    float* out  = (float*)d_out;
    float* hout = out + HOUT_OFF;
    float* xout = out + XOUT_OFF;
    float* mz   = out + M_OFF;                        // z1 (bf16 in-slot), then m (fp32)
    unsigned short* zG = (unsigned short*)mz;
    float* ws   = (float*)d_ws;
    float* sRed = xout;
    float* qRed = xout + 4608;

    hipMemsetAsync(ws, 0, (size_t)WS_ZERO_END * 4, stream);
    hipMemsetAsync(ws + WS_HIST, 0, 4096 * 4, stream);
    k_nodeproj<<<128, 256, 0, stream>>>(h, We1, ws + WS_ZH1, ws + WS_MAGG);
    k_edge1v4<<<2048, 256, 0, stream>>>(x, ei, ej, ws + WS_ZH1, ws + WS_MAGG, We1,
                                        zG, (int*)(ws + WS_HIST));
    k_scan<<<32, 128, 0, stream>>>((const int*)(ws + WS_HIST), (int*)(ws + WS_OFFS),
                                   (int*)(ws + WS_CURS), ws + WS_CNT);
    k_scatter<<<2048, 256, 0, stream>>>(ei, (int*)(ws + WS_CURS),
                                        (unsigned short*)(ws + WS_PERM));
    k_stats_bf<<<576, 256, 0, stream>>>(zG, ws + WS_MAGG, ws + WS_MAGG + NSTAT_T);
    k_red<<<18, 256, 0, stream>>>(ws + WS_MAGG, ws + WS_MAGG + NSTAT_T, sRed, qRed);
    k_fin2c<<<1, 288, 0, stream>>>(sRed, qRed, ge, bee,
                                   ws + WS_AE, ws + WS_BE, 1.0f / (float)(B_ * E_));
    k_e2f<<<2048, 256, 0, stream>>>(x, ei, ej, We2, be2, Wm, bm, bx1, Wx1, Wx2,
                                    ws + WS_AE, ws + WS_BE, zG, mz, ws + WS_AGG);
    k_seg2<<<1152, 256, 0, stream>>>(mz, (const unsigned short*)(ws + WS_PERM),
                                     (const int*)(ws + WS_OFFS), (const int*)(ws + WS_HIST),
                                     ws + WS_MAGG);
    k_node1v3<<<128, 256, 0, stream>>>(h, ws + WS_MAGG, attr, Wh1, bh1, ws + WS_ZH1);
    k_stats<<<576, 256, 0, stream>>>(ws + WS_ZH1, hout, hout + NSTAT_T, 2);
    k_red<<<18, 256, 0, stream>>>(hout, hout + NSTAT_T, sRed, qRed);
    k_fin2c<<<1, 288, 0, stream>>>(sRed, qRed, gh, beh,
                                   ws + WS_AH, ws + WS_BH, 1.0f / 4096.0f);
    k_node2v2<<<128, 256, 0, stream>>>(h, x, ws + WS_ZH1, ws + WS_AH, ws + WS_BH, Wh2, bh2,
                                       ws + WS_AGG, ws + WS_CNT, hout, xout);
}